// Round 9
// baseline (270.525 us; speedup 1.0000x reference)
//
#include <hip/hip_runtime.h>
#include <hip/hip_bf16.h>
#include <hip/hip_cooperative_groups.h>

namespace cg = cooperative_groups;

#define N_NODES 8192
#define DIN     256
#define DOUT    128
#define NHEAD   2
#define CTOT    256          // NHEAD*DOUT, flat channel dim
#define NWORDS  256          // N_NODES/32 bitmask words per row
#define LRELU_A 0.2f
#define CAP     512          // max supported degree (actual max ~66)
#define LDR     40           // LDS row stride (80B = 5x16B, ds_read_b128 conflict-free)

typedef __attribute__((ext_vector_type(8))) short bf16x8;
typedef __attribute__((ext_vector_type(4))) float f32x4;

__device__ __forceinline__ float bf(unsigned short u) {
    return __uint_as_float((unsigned)u << 16);
}
__device__ __forceinline__ unsigned short f2bf(float f) {
    unsigned u = __float_as_uint(f);
    u = (u + 0x7fffu + ((u >> 16) & 1u)) >> 16;
    return (unsigned short)u;
}
__device__ __forceinline__ unsigned pk(float a, float b) {
    return (unsigned)f2bf(a) | ((unsigned)f2bf(b) << 16);
}

// =============================================================================
// Cooperative mega-kernel: whole pipeline, 2 grid syncs.
//   P0: blocks [0,256) MFMA GEMM tile; blocks [256,ng) clear adjw (+S_all).
//   P1: blocks [0,256) fused scores+colsum; blocks [256,ng) edge scatter.
//   P2: all blocks: attention rows i = b, b+ng, ...
// =============================================================================
__global__ __launch_bounds__(256, 4) void k_mega(const float* __restrict__ x,
                                                 const float* __restrict__ W,
                                                 const float* __restrict__ a,
                                                 const int* __restrict__ ei, int E,
                                                 unsigned int* __restrict__ adjw,
                                                 float* __restrict__ S_all,
                                                 float* __restrict__ s_src,
                                                 float* __restrict__ s_dst,
                                                 unsigned short* __restrict__ hb16,
                                                 float* __restrict__ out) {
    __shared__ union SMem {
        struct { unsigned short As[128 * LDR]; unsigned short Bs[64 * LDR]; } g;
        struct { unsigned short nbr[CAP]; float ew0[CAP]; float ew1[CAP];
                 int wtot[4]; float zr0[4]; float zr1[4]; } at;
        float4 cpart[4][64];
    } sm;

    cg::grid_group grid = cg::this_grid();
    int b = blockIdx.x, t = threadIdx.x;
    int ng = gridDim.x;
    int wv = t >> 6, lane = t & 63;

    // ---------------- P0 ----------------
    if (b < 256) {
        // MFMA bf16 GEMM, tile 128x64, K-step 32 (frag layout m89/m91-verified)
        int bm = (b & 63) * 128;
        int bn = (b >> 6) * 64;
        int fr = lane & 15, ksl = lane >> 4;
        f32x4 acc[2][4] = {};
        for (int k0 = 0; k0 < DIN; k0 += 32) {
            #pragma unroll
            for (int i = 0; i < 2; ++i) {
                int idx = i * 256 + t;
                int row = idx >> 2, slot = idx & 3;
                const float4* src = reinterpret_cast<const float4*>(&x[(bm + row) * DIN + k0 + slot * 8]);
                float4 v0 = src[0], v1 = src[1];
                uint4 q = make_uint4(pk(v0.x, v0.y), pk(v0.z, v0.w), pk(v1.x, v1.y), pk(v1.z, v1.w));
                *reinterpret_cast<uint4*>(&sm.g.As[row * LDR + slot * 8]) = q;
            }
            {
                int row = t >> 2, slot = t & 3;
                const float4* src = reinterpret_cast<const float4*>(&W[(bn + row) * DIN + k0 + slot * 8]);
                float4 v0 = src[0], v1 = src[1];
                uint4 q = make_uint4(pk(v0.x, v0.y), pk(v0.z, v0.w), pk(v1.x, v1.y), pk(v1.z, v1.w));
                *reinterpret_cast<uint4*>(&sm.g.Bs[row * LDR + slot * 8]) = q;
            }
            __syncthreads();
            bf16x8 af[2], bfr[4];
            #pragma unroll
            for (int fm = 0; fm < 2; ++fm)
                af[fm] = *reinterpret_cast<const bf16x8*>(&sm.g.As[(wv * 32 + fm * 16 + fr) * LDR + ksl * 8]);
            #pragma unroll
            for (int fn = 0; fn < 4; ++fn)
                bfr[fn] = *reinterpret_cast<const bf16x8*>(&sm.g.Bs[(fn * 16 + fr) * LDR + ksl * 8]);
            #pragma unroll
            for (int fm = 0; fm < 2; ++fm)
                #pragma unroll
                for (int fn = 0; fn < 4; ++fn)
                    acc[fm][fn] = __builtin_amdgcn_mfma_f32_16x16x32_bf16(af[fm], bfr[fn], acc[fm][fn], 0, 0, 0);
            __syncthreads();
        }
        #pragma unroll
        for (int fm = 0; fm < 2; ++fm) {
            int r0 = bm + wv * 32 + fm * 16 + ksl * 4;
            #pragma unroll
            for (int fn = 0; fn < 4; ++fn) {
                int c = bn + fn * 16 + fr;
                #pragma unroll
                for (int r = 0; r < 4; ++r)
                    hb16[(size_t)(r0 + r) * CTOT + c] = f2bf(acc[fm][fn][r]);
            }
        }
    } else {
        // clear adj bitmask (524288 float4) + S_all
        float4* adjp = reinterpret_cast<float4*>(adjw);
        const float4 z = make_float4(0.f, 0.f, 0.f, 0.f);
        for (int idx = (b - 256) * 256 + t; idx < N_NODES * NWORDS / 4; idx += (ng - 256) * 256)
            adjp[idx] = z;
        if (b == 256 && t < 64)
            reinterpret_cast<float4*>(S_all)[t] = z;
    }

    grid.sync();

    // ---------------- P1 ----------------
    if (b < 256) {
        // fused scores + column sum over hb16 (32 rows per block)
        int head = lane >> 5;
        int cb = (lane & 31) * 4;
        const float4 as4 = *reinterpret_cast<const float4*>(&a[head * 256 + cb]);
        const float4 ad4 = *reinterpret_cast<const float4*>(&a[head * 256 + 128 + cb]);
        const uint2* hb16v = reinterpret_cast<const uint2*>(hb16);
        int r0 = b * 32 + wv * 8;
        float4 cs = make_float4(0.f, 0.f, 0.f, 0.f);
        for (int r = r0; r < r0 + 8; ++r) {
            uint2 hv = hb16v[r * 64 + lane];
            float f0 = bf((unsigned short)hv.x), f1 = bf((unsigned short)(hv.x >> 16));
            float f2 = bf((unsigned short)hv.y), f3 = bf((unsigned short)(hv.y >> 16));
            cs.x += f0; cs.y += f1; cs.z += f2; cs.w += f3;
            float ps = f0 * as4.x + f1 * as4.y + f2 * as4.z + f3 * as4.w;
            float pd = f0 * ad4.x + f1 * ad4.y + f2 * ad4.z + f3 * ad4.w;
            #pragma unroll
            for (int off = 16; off; off >>= 1) {
                ps += __shfl_xor(ps, off);
                pd += __shfl_xor(pd, off);
            }
            if ((lane & 31) == 0) {
                s_src[head * N_NODES + r] = ps;
                s_dst[head * N_NODES + r] = pd;
            }
        }
        sm.cpart[wv][lane] = cs;
        __syncthreads();
        if (t < 64) {
            float4 c0 = sm.cpart[0][t], c1 = sm.cpart[1][t], c2 = sm.cpart[2][t], c3 = sm.cpart[3][t];
            atomicAdd(&S_all[t * 4 + 0], c0.x + c1.x + c2.x + c3.x);
            atomicAdd(&S_all[t * 4 + 1], c0.y + c1.y + c2.y + c3.y);
            atomicAdd(&S_all[t * 4 + 2], c0.z + c1.z + c2.z + c3.z);
            atomicAdd(&S_all[t * 4 + 3], c0.w + c1.w + c2.w + c3.w);
        }
    } else {
        // edge scatter (dedup via atomicOr)
        for (int e = (b - 256) * 256 + t; e < E; e += (ng - 256) * 256) {
            int src = ei[e];
            int dst = ei[E + e];
            atomicOr(&adjw[(size_t)src * NWORDS + (dst >> 5)], 1u << (dst & 31));
        }
    }

    grid.sync();

    // ---------------- P2: attention rows ----------------
    for (int i = b; i < N_NODES; i += ng) {
        __syncthreads();   // protect LDS reuse across row iterations

        unsigned int w = adjw[(size_t)i * NWORDS + t];
        int cnt = __popc(w);
        int inc = cnt;
        #pragma unroll
        for (int off = 1; off < 64; off <<= 1) {
            int v = __shfl_up(inc, off);
            if (lane >= off) inc += v;
        }
        if (lane == 63) sm.at.wtot[wv] = inc;
        __syncthreads();
        int base = 0;
        #pragma unroll
        for (int q = 0; q < 3; ++q) if (q < wv) base += sm.at.wtot[q];
        int deg = sm.at.wtot[0] + sm.at.wtot[1] + sm.at.wtot[2] + sm.at.wtot[3];
        int pos = base + inc - cnt;
        unsigned int ww = w;
        while (ww) {
            int bb = __ffs(ww) - 1;
            ww &= ww - 1;
            if (pos < CAP) sm.at.nbr[pos] = (unsigned short)(t * 32 + bb);
            ++pos;
        }
        if (deg > CAP) deg = CAP;
        __syncthreads();

        float ss0 = s_src[i], ss1 = s_src[N_NODES + i];
        float z0 = 0.f, z1 = 0.f;
        for (int k = t; k < deg; k += 256) {
            int j = sm.at.nbr[k];
            float v0 = ss0 + s_dst[j];
            float v1 = ss1 + s_dst[N_NODES + j];
            float e0 = v0 > 0.f ? v0 : LRELU_A * v0;
            float e1 = v1 > 0.f ? v1 : LRELU_A * v1;
            float w0 = expf(e0) - 1.f;
            float w1 = expf(e1) - 1.f;
            sm.at.ew0[k] = w0; sm.at.ew1[k] = w1;
            z0 += w0; z1 += w1;
        }
        #pragma unroll
        for (int off = 32; off; off >>= 1) {
            z0 += __shfl_xor(z0, off);
            z1 += __shfl_xor(z1, off);
        }
        if (lane == 0) { sm.at.zr0[wv] = z0; sm.at.zr1[wv] = z1; }
        __syncthreads();
        float Z0 = (float)N_NODES + sm.at.zr0[0] + sm.at.zr0[1] + sm.at.zr0[2] + sm.at.zr0[3];
        float Z1 = (float)N_NODES + sm.at.zr1[0] + sm.at.zr1[1] + sm.at.zr1[2] + sm.at.zr1[3];

        int hh = t >> 7;
        const float* ewh = hh ? sm.at.ew1 : sm.at.ew0;
        float Zh = hh ? Z1 : Z0;
        float acc = 0.f;
        int k = 0;
        for (; k + 8 <= deg; k += 8) {
            int j0 = sm.at.nbr[k+0], j1 = sm.at.nbr[k+1], j2 = sm.at.nbr[k+2], j3 = sm.at.nbr[k+3];
            int j4 = sm.at.nbr[k+4], j5 = sm.at.nbr[k+5], j6 = sm.at.nbr[k+6], j7 = sm.at.nbr[k+7];
            float w0 = ewh[k+0], w1 = ewh[k+1], w2 = ewh[k+2], w3 = ewh[k+3];
            float w4 = ewh[k+4], w5 = ewh[k+5], w6 = ewh[k+6], w7 = ewh[k+7];
            float v0 = bf(hb16[j0 * CTOT + t]);
            float v1 = bf(hb16[j1 * CTOT + t]);
            float v2 = bf(hb16[j2 * CTOT + t]);
            float v3 = bf(hb16[j3 * CTOT + t]);
            float v4 = bf(hb16[j4 * CTOT + t]);
            float v5 = bf(hb16[j5 * CTOT + t]);
            float v6 = bf(hb16[j6 * CTOT + t]);
            float v7 = bf(hb16[j7 * CTOT + t]);
            acc = fmaf(w0, v0, acc); acc = fmaf(w1, v1, acc);
            acc = fmaf(w2, v2, acc); acc = fmaf(w3, v3, acc);
            acc = fmaf(w4, v4, acc); acc = fmaf(w5, v5, acc);
            acc = fmaf(w6, v6, acc); acc = fmaf(w7, v7, acc);
        }
        for (; k + 4 <= deg; k += 4) {
            int j0 = sm.at.nbr[k], j1 = sm.at.nbr[k+1], j2 = sm.at.nbr[k+2], j3 = sm.at.nbr[k+3];
            float w0 = ewh[k], w1 = ewh[k+1], w2 = ewh[k+2], w3 = ewh[k+3];
            float v0 = bf(hb16[j0 * CTOT + t]);
            float v1 = bf(hb16[j1 * CTOT + t]);
            float v2 = bf(hb16[j2 * CTOT + t]);
            float v3 = bf(hb16[j3 * CTOT + t]);
            acc = fmaf(w0, v0, acc); acc = fmaf(w1, v1, acc);
            acc = fmaf(w2, v2, acc); acc = fmaf(w3, v3, acc);
        }
        for (; k < deg; ++k)
            acc = fmaf(ewh[k], bf(hb16[sm.at.nbr[k] * CTOT + t]), acc);

        float o = (S_all[t] + acc) / Zh;
        o = o > 0.f ? o : expm1f(o);       // ELU (alpha=1)
        out[i * CTOT + t] = o;
    }
}

// =============================================================================
// Fallback path: R8's three kernels (used only if cooperative launch unavailable)
// =============================================================================
__global__ __launch_bounds__(256) void k_pre(const float* __restrict__ x,
                                             const float* __restrict__ W,
                                             unsigned short* __restrict__ hb16,
                                             float4* __restrict__ adjp,
                                             float4* __restrict__ sallp) {
    __shared__ unsigned short As[128 * LDR];
    __shared__ unsigned short Bs[64 * LDR];
    int b = blockIdx.x, t = threadIdx.x;
    if (b < 2048) { adjp[b * 256 + t] = make_float4(0.f, 0.f, 0.f, 0.f); return; }
    if (b == 2048) { if (t < 64) sallp[t] = make_float4(0.f, 0.f, 0.f, 0.f); return; }
    int g = b - 2049;
    int bm = (g & 63) * 128, bn = (g >> 6) * 64;
    int wv = t >> 6, lane = t & 63;
    int fr = lane & 15, ksl = lane >> 4;
    f32x4 acc[2][4] = {};
    for (int k0 = 0; k0 < DIN; k0 += 32) {
        #pragma unroll
        for (int i = 0; i < 2; ++i) {
            int idx = i * 256 + t;
            int row = idx >> 2, slot = idx & 3;
            const float4* src = reinterpret_cast<const float4*>(&x[(bm + row) * DIN + k0 + slot * 8]);
            float4 v0 = src[0], v1 = src[1];
            *reinterpret_cast<uint4*>(&As[row * LDR + slot * 8]) =
                make_uint4(pk(v0.x, v0.y), pk(v0.z, v0.w), pk(v1.x, v1.y), pk(v1.z, v1.w));
        }
        {
            int row = t >> 2, slot = t & 3;
            const float4* src = reinterpret_cast<const float4*>(&W[(bn + row) * DIN + k0 + slot * 8]);
            float4 v0 = src[0], v1 = src[1];
            *reinterpret_cast<uint4*>(&Bs[row * LDR + slot * 8]) =
                make_uint4(pk(v0.x, v0.y), pk(v0.z, v0.w), pk(v1.x, v1.y), pk(v1.z, v1.w));
        }
        __syncthreads();
        bf16x8 af[2], bfr[4];
        #pragma unroll
        for (int fm = 0; fm < 2; ++fm)
            af[fm] = *reinterpret_cast<const bf16x8*>(&As[(wv * 32 + fm * 16 + fr) * LDR + ksl * 8]);
        #pragma unroll
        for (int fn = 0; fn < 4; ++fn)
            bfr[fn] = *reinterpret_cast<const bf16x8*>(&Bs[(fn * 16 + fr) * LDR + ksl * 8]);
        #pragma unroll
        for (int fm = 0; fm < 2; ++fm)
            #pragma unroll
            for (int fn = 0; fn < 4; ++fn)
                acc[fm][fn] = __builtin_amdgcn_mfma_f32_16x16x32_bf16(af[fm], bfr[fn], acc[fm][fn], 0, 0, 0);
        __syncthreads();
    }
    #pragma unroll
    for (int fm = 0; fm < 2; ++fm) {
        int r0 = bm + wv * 32 + fm * 16 + ksl * 4;
        #pragma unroll
        for (int fn = 0; fn < 4; ++fn) {
            int c = bn + fn * 16 + fr;
            #pragma unroll
            for (int r = 0; r < 4; ++r)
                hb16[(size_t)(r0 + r) * CTOT + c] = f2bf(acc[fm][fn][r]);
        }
    }
}

__global__ __launch_bounds__(256) void k_mid(const int* __restrict__ ei, int E, int nbBuild,
                                             unsigned int* __restrict__ adjw,
                                             const uint2* __restrict__ hb16v,
                                             const float* __restrict__ a,
                                             float* __restrict__ s_src,
                                             float* __restrict__ s_dst,
                                             float* __restrict__ S_all) {
    __shared__ float4 cpart[4][64];
    int b = blockIdx.x, t = threadIdx.x;
    if (b < nbBuild) {
        int e = b * 256 + t;
        if (e < E) {
            int src = ei[e];
            int dst = ei[E + e];
            atomicOr(&adjw[(size_t)src * NWORDS + (dst >> 5)], 1u << (dst & 31));
        }
        return;
    }
    int blk = b - nbBuild;
    int wv = t >> 6, lane = t & 63;
    int head = lane >> 5;
    int cb = (lane & 31) * 4;
    const float4 as4 = *reinterpret_cast<const float4*>(&a[head * 256 + cb]);
    const float4 ad4 = *reinterpret_cast<const float4*>(&a[head * 256 + 128 + cb]);
    int r0 = blk * 32 + wv * 8;
    float4 cs = make_float4(0.f, 0.f, 0.f, 0.f);
    for (int r = r0; r < r0 + 8; ++r) {
        uint2 hv = hb16v[r * 64 + lane];
        float f0 = bf((unsigned short)hv.x), f1 = bf((unsigned short)(hv.x >> 16));
        float f2 = bf((unsigned short)hv.y), f3 = bf((unsigned short)(hv.y >> 16));
        cs.x += f0; cs.y += f1; cs.z += f2; cs.w += f3;
        float ps = f0 * as4.x + f1 * as4.y + f2 * as4.z + f3 * as4.w;
        float pd = f0 * ad4.x + f1 * ad4.y + f2 * ad4.z + f3 * ad4.w;
        #pragma unroll
        for (int off = 16; off; off >>= 1) {
            ps += __shfl_xor(ps, off);
            pd += __shfl_xor(pd, off);
        }
        if ((lane & 31) == 0) {
            s_src[head * N_NODES + r] = ps;
            s_dst[head * N_NODES + r] = pd;
        }
    }
    cpart[wv][lane] = cs;
    __syncthreads();
    if (t < 64) {
        float4 c0 = cpart[0][t], c1 = cpart[1][t], c2 = cpart[2][t], c3 = cpart[3][t];
        atomicAdd(&S_all[t * 4 + 0], c0.x + c1.x + c2.x + c3.x);
        atomicAdd(&S_all[t * 4 + 1], c0.y + c1.y + c2.y + c3.y);
        atomicAdd(&S_all[t * 4 + 2], c0.z + c1.z + c2.z + c3.z);
        atomicAdd(&S_all[t * 4 + 3], c0.w + c1.w + c2.w + c3.w);
    }
}

__global__ __launch_bounds__(256) void k_attn(const unsigned int* __restrict__ adjw,
                                              const float* __restrict__ s_src,
                                              const float* __restrict__ s_dst,
                                              const unsigned short* __restrict__ hb16,
                                              const float* __restrict__ S_all,
                                              float* __restrict__ out) {
    __shared__ unsigned short nbr[CAP];
    __shared__ float          ew0[CAP];
    __shared__ float          ew1[CAP];
    __shared__ int            wtot[4];
    __shared__ float          zr0[4];
    __shared__ float          zr1[4];
    int i = blockIdx.x, t = threadIdx.x, lane = t & 63, wv = t >> 6;
    unsigned int w = adjw[(size_t)i * NWORDS + t];
    int cnt = __popc(w);
    int inc = cnt;
    #pragma unroll
    for (int off = 1; off < 64; off <<= 1) {
        int v = __shfl_up(inc, off);
        if (lane >= off) inc += v;
    }
    if (lane == 63) wtot[wv] = inc;
    __syncthreads();
    int base = 0;
    #pragma unroll
    for (int q = 0; q < 3; ++q) if (q < wv) base += wtot[q];
    int deg = wtot[0] + wtot[1] + wtot[2] + wtot[3];
    int pos = base + inc - cnt;
    unsigned int ww = w;
    while (ww) {
        int b = __ffs(ww) - 1;
        ww &= ww - 1;
        if (pos < CAP) nbr[pos] = (unsigned short)(t * 32 + b);
        ++pos;
    }
    if (deg > CAP) deg = CAP;
    __syncthreads();
    float ss0 = s_src[i], ss1 = s_src[N_NODES + i];
    float z0 = 0.f, z1 = 0.f;
    for (int k = t; k < deg; k += 256) {
        int j = nbr[k];
        float v0 = ss0 + s_dst[j];
        float v1 = ss1 + s_dst[N_NODES + j];
        float e0 = v0 > 0.f ? v0 : LRELU_A * v0;
        float e1 = v1 > 0.f ? v1 : LRELU_A * v1;
        float w0 = expf(e0) - 1.f;
        float w1 = expf(e1) - 1.f;
        ew0[k] = w0; ew1[k] = w1;
        z0 += w0; z1 += w1;
    }
    #pragma unroll
    for (int off = 32; off; off >>= 1) {
        z0 += __shfl_xor(z0, off);
        z1 += __shfl_xor(z1, off);
    }
    if (lane == 0) { zr0[wv] = z0; zr1[wv] = z1; }
    __syncthreads();
    float Z0 = (float)N_NODES + zr0[0] + zr0[1] + zr0[2] + zr0[3];
    float Z1 = (float)N_NODES + zr1[0] + zr1[1] + zr1[2] + zr1[3];
    int hh = t >> 7;
    const float* ewh = hh ? ew1 : ew0;
    float Zh = hh ? Z1 : Z0;
    float acc = 0.f;
    int k = 0;
    for (; k + 8 <= deg; k += 8) {
        int j0 = nbr[k+0], j1 = nbr[k+1], j2 = nbr[k+2], j3 = nbr[k+3];
        int j4 = nbr[k+4], j5 = nbr[k+5], j6 = nbr[k+6], j7 = nbr[k+7];
        float w0 = ewh[k+0], w1 = ewh[k+1], w2 = ewh[k+2], w3 = ewh[k+3];
        float w4 = ewh[k+4], w5 = ewh[k+5], w6 = ewh[k+6], w7 = ewh[k+7];
        float v0 = bf(hb16[j0 * CTOT + t]);
        float v1 = bf(hb16[j1 * CTOT + t]);
        float v2 = bf(hb16[j2 * CTOT + t]);
        float v3 = bf(hb16[j3 * CTOT + t]);
        float v4 = bf(hb16[j4 * CTOT + t]);
        float v5 = bf(hb16[j5 * CTOT + t]);
        float v6 = bf(hb16[j6 * CTOT + t]);
        float v7 = bf(hb16[j7 * CTOT + t]);
        acc = fmaf(w0, v0, acc); acc = fmaf(w1, v1, acc);
        acc = fmaf(w2, v2, acc); acc = fmaf(w3, v3, acc);
        acc = fmaf(w4, v4, acc); acc = fmaf(w5, v5, acc);
        acc = fmaf(w6, v6, acc); acc = fmaf(w7, v7, acc);
    }
    for (; k + 4 <= deg; k += 4) {
        int j0 = nbr[k], j1 = nbr[k+1], j2 = nbr[k+2], j3 = nbr[k+3];
        float w0 = ewh[k], w1 = ewh[k+1], w2 = ewh[k+2], w3 = ewh[k+3];
        float v0 = bf(hb16[j0 * CTOT + t]);
        float v1 = bf(hb16[j1 * CTOT + t]);
        float v2 = bf(hb16[j2 * CTOT + t]);
        float v3 = bf(hb16[j3 * CTOT + t]);
        acc = fmaf(w0, v0, acc); acc = fmaf(w1, v1, acc);
        acc = fmaf(w2, v2, acc); acc = fmaf(w3, v3, acc);
    }
    for (; k < deg; ++k)
        acc = fmaf(ewh[k], bf(hb16[nbr[k] * CTOT + t]), acc);
    float o = (S_all[t] + acc) / Zh;
    o = o > 0.f ? o : expm1f(o);
    out[i * CTOT + t] = o;
}

// ---------------- launch ------------------------------------------------------
extern "C" void kernel_launch(void* const* d_in, const int* in_sizes, int n_in,
                              void* d_out, int out_size, void* d_ws, size_t ws_size,
                              hipStream_t stream) {
    const float* x  = (const float*)d_in[0];
    const float* W  = (const float*)d_in[1];
    const float* a  = (const float*)d_in[2];
    const int*   ei = (const int*)d_in[3];
    int E = in_sizes[3] / 2;
    float* out = (float*)d_out;

    char* ws = (char*)d_ws;
    size_t off = 0;
    auto alloc = [&](size_t bytes) { char* p = ws + off; off += (bytes + 255) & ~(size_t)255; return p; };
    unsigned int*   adjw  = (unsigned int*)  alloc((size_t)N_NODES * NWORDS * 4); // 8 MB
    float*          S_all = (float*)         alloc(CTOT * 4);
    float*          s_src = (float*)         alloc((size_t)NHEAD * N_NODES * 4);
    float*          s_dst = (float*)         alloc((size_t)NHEAD * N_NODES * 4);
    unsigned short* hb16  = (unsigned short*)alloc((size_t)N_NODES * CTOT * 2);  // 4 MB

    // capture-safe host-side queries (no stream ops)
    int coop = 0;
    hipDeviceGetAttribute(&coop, hipDeviceAttributeCooperativeLaunch, 0);
    int nCU = 0;
    hipDeviceGetAttribute(&nCU, hipDeviceAttributeMultiprocessorCount, 0);
    int maxb = 0;
    hipError_t oe = hipOccupancyMaxActiveBlocksPerMultiprocessor(&maxb, k_mega, 256, 0);

    int ng = maxb * nCU;
    if (ng > 1024) ng = 1024;

    if (coop && oe == hipSuccess && ng >= 512) {
        void* args[] = {(void*)&x, (void*)&W, (void*)&a, (void*)&ei, (void*)&E,
                        (void*)&adjw, (void*)&S_all, (void*)&s_src, (void*)&s_dst,
                        (void*)&hb16, (void*)&out};
        hipError_t err = hipLaunchCooperativeKernel((const void*)k_mega, dim3(ng), dim3(256),
                                                    args, 0, stream);
        if (err == hipSuccess) return;
    }

    // fallback: R8 three-kernel pipeline
    int nbBuild = (E + 255) / 256;
    k_pre<<<2305, 256, 0, stream>>>(x, W, hb16, (float4*)adjw, (float4*)S_all);
    k_mid<<<nbBuild + 256, 256, 0, stream>>>(ei, E, nbBuild, adjw,
                                             (const uint2*)hb16, a, s_src, s_dst, S_all);
    k_attn<<<N_NODES, 256, 0, stream>>>(adjw, s_src, s_dst, hb16, S_all, out);
}

// Round 10
// 84.552 us; speedup vs baseline: 3.1995x; 3.1995x over previous
//
#include <hip/hip_runtime.h>
#include <hip/hip_bf16.h>

#define N_NODES 8192
#define DIN     256
#define DOUT    128
#define NHEAD   2
#define CTOT    256          // NHEAD*DOUT, flat channel dim
#define NWORDS  256          // N_NODES/32 bitmask words per row
#define LRELU_A 0.2f
#define CAPN    96           // max degree (Binomial mean 32, sd 5.7; max over 8k rows ~56)
#define LDR     40           // LDS row stride (80B = 5x16B, ds_read_b128 conflict-free)

typedef __attribute__((ext_vector_type(8))) short bf16x8;
typedef __attribute__((ext_vector_type(4))) float f32x4;

__device__ __forceinline__ float bf(unsigned short u) {
    return __uint_as_float((unsigned)u << 16);
}
__device__ __forceinline__ unsigned short f2bf(float f) {
    unsigned u = __float_as_uint(f);
    u = (u + 0x7fffu + ((u >> 16) & 1u)) >> 16;
    return (unsigned short)u;
}
__device__ __forceinline__ unsigned pk(float a, float b) {
    return (unsigned)f2bf(a) | ((unsigned)f2bf(b) << 16);
}

// =============================================================================
// K1: blocks [0,2048) clear adj bitmask; block 2048 clears S_all;
//     blocks [2049,2305) MFMA bf16 GEMM (tile 128x64, K-step 32).
// =============================================================================
__global__ __launch_bounds__(256) void k_pre(const float* __restrict__ x,
                                             const float* __restrict__ W,
                                             unsigned short* __restrict__ hb16,
                                             float4* __restrict__ adjp,
                                             float4* __restrict__ sallp) {
    __shared__ unsigned short As[128 * LDR];
    __shared__ unsigned short Bs[64 * LDR];
    int b = blockIdx.x, t = threadIdx.x;
    if (b < 2048) { adjp[b * 256 + t] = make_float4(0.f, 0.f, 0.f, 0.f); return; }
    if (b == 2048) { if (t < 64) sallp[t] = make_float4(0.f, 0.f, 0.f, 0.f); return; }
    int g = b - 2049;
    int bm = (g & 63) * 128, bn = (g >> 6) * 64;
    int wv = t >> 6, lane = t & 63;
    int fr = lane & 15, ksl = lane >> 4;
    f32x4 acc[2][4] = {};
    for (int k0 = 0; k0 < DIN; k0 += 32) {
        #pragma unroll
        for (int i = 0; i < 2; ++i) {
            int idx = i * 256 + t;
            int row = idx >> 2, slot = idx & 3;
            const float4* src = reinterpret_cast<const float4*>(&x[(bm + row) * DIN + k0 + slot * 8]);
            float4 v0 = src[0], v1 = src[1];
            *reinterpret_cast<uint4*>(&As[row * LDR + slot * 8]) =
                make_uint4(pk(v0.x, v0.y), pk(v0.z, v0.w), pk(v1.x, v1.y), pk(v1.z, v1.w));
        }
        {
            int row = t >> 2, slot = t & 3;
            const float4* src = reinterpret_cast<const float4*>(&W[(bn + row) * DIN + k0 + slot * 8]);
            float4 v0 = src[0], v1 = src[1];
            *reinterpret_cast<uint4*>(&Bs[row * LDR + slot * 8]) =
                make_uint4(pk(v0.x, v0.y), pk(v0.z, v0.w), pk(v1.x, v1.y), pk(v1.z, v1.w));
        }
        __syncthreads();
        bf16x8 af[2], bfr[4];
        #pragma unroll
        for (int fm = 0; fm < 2; ++fm)
            af[fm] = *reinterpret_cast<const bf16x8*>(&As[(wv * 32 + fm * 16 + fr) * LDR + ksl * 8]);
        #pragma unroll
        for (int fn = 0; fn < 4; ++fn)
            bfr[fn] = *reinterpret_cast<const bf16x8*>(&Bs[(fn * 16 + fr) * LDR + ksl * 8]);
        #pragma unroll
        for (int fm = 0; fm < 2; ++fm)
            #pragma unroll
            for (int fn = 0; fn < 4; ++fn)
                acc[fm][fn] = __builtin_amdgcn_mfma_f32_16x16x32_bf16(af[fm], bfr[fn], acc[fm][fn], 0, 0, 0);
        __syncthreads();
    }
    #pragma unroll
    for (int fm = 0; fm < 2; ++fm) {
        int r0 = bm + wv * 32 + fm * 16 + ksl * 4;
        #pragma unroll
        for (int fn = 0; fn < 4; ++fn) {
            int c = bn + fn * 16 + fr;
            #pragma unroll
            for (int r = 0; r < 4; ++r)
                hb16[(size_t)(r0 + r) * CTOT + c] = f2bf(acc[fm][fn][r]);
        }
    }
}

// =============================================================================
// K2: blocks [0,nbBuild) edge scatter (atomicOr dedup);
//     blocks [nbBuild,nbBuild+256) fused scores + column sum over hb16.
// =============================================================================
__global__ __launch_bounds__(256) void k_mid(const int* __restrict__ ei, int E, int nbBuild,
                                             unsigned int* __restrict__ adjw,
                                             const uint2* __restrict__ hb16v,
                                             const float* __restrict__ a,
                                             float* __restrict__ s_src,
                                             float* __restrict__ s_dst,
                                             float* __restrict__ S_all) {
    __shared__ float4 cpart[4][64];
    int b = blockIdx.x, t = threadIdx.x;
    if (b < nbBuild) {
        int e = b * 256 + t;
        if (e < E) {
            int src = ei[e];
            int dst = ei[E + e];
            atomicOr(&adjw[(size_t)src * NWORDS + (dst >> 5)], 1u << (dst & 31));
        }
        return;
    }
    int blk = b - nbBuild;
    int wv = t >> 6, lane = t & 63;
    int head = lane >> 5;
    int cb = (lane & 31) * 4;
    const float4 as4 = *reinterpret_cast<const float4*>(&a[head * 256 + cb]);
    const float4 ad4 = *reinterpret_cast<const float4*>(&a[head * 256 + 128 + cb]);
    int r0 = blk * 32 + wv * 8;
    float4 cs = make_float4(0.f, 0.f, 0.f, 0.f);
    for (int r = r0; r < r0 + 8; ++r) {
        uint2 hv = hb16v[r * 64 + lane];
        float f0 = bf((unsigned short)hv.x), f1 = bf((unsigned short)(hv.x >> 16));
        float f2 = bf((unsigned short)hv.y), f3 = bf((unsigned short)(hv.y >> 16));
        cs.x += f0; cs.y += f1; cs.z += f2; cs.w += f3;
        float ps = f0 * as4.x + f1 * as4.y + f2 * as4.z + f3 * as4.w;
        float pd = f0 * ad4.x + f1 * ad4.y + f2 * ad4.z + f3 * ad4.w;
        #pragma unroll
        for (int off = 16; off; off >>= 1) {
            ps += __shfl_xor(ps, off);
            pd += __shfl_xor(pd, off);
        }
        if ((lane & 31) == 0) {
            s_src[head * N_NODES + r] = ps;
            s_dst[head * N_NODES + r] = pd;
        }
    }
    cpart[wv][lane] = cs;
    __syncthreads();
    if (t < 64) {
        float4 c0 = cpart[0][t], c1 = cpart[1][t], c2 = cpart[2][t], c3 = cpart[3][t];
        atomicAdd(&S_all[t * 4 + 0], c0.x + c1.x + c2.x + c3.x);
        atomicAdd(&S_all[t * 4 + 1], c0.y + c1.y + c2.y + c3.y);
        atomicAdd(&S_all[t * 4 + 2], c0.z + c1.z + c2.z + c3.z);
        atomicAdd(&S_all[t * 4 + 3], c0.w + c1.w + c2.w + c3.w);
    }
}

// =============================================================================
// K3: wave-per-row CSR build — compaction + per-edge weights + Z (R4-proven).
// =============================================================================
__global__ __launch_bounds__(256) void k_cw(const unsigned int* __restrict__ adjw,
                                            const float* __restrict__ s_src,
                                            const float* __restrict__ s_dst,
                                            unsigned short* __restrict__ nbrG,
                                            float* __restrict__ wG0,
                                            float* __restrict__ wG1,
                                            int*   __restrict__ degG,
                                            float* __restrict__ ZG0,
                                            float* __restrict__ ZG1) {
    int t    = threadIdx.x;
    int wv   = t >> 6;
    int lane = t & 63;
    int i    = blockIdx.x * 4 + wv;

    const uint4 wq = reinterpret_cast<const uint4*>(adjw + (size_t)i * NWORDS)[lane];
    int cnt = __popc(wq.x) + __popc(wq.y) + __popc(wq.z) + __popc(wq.w);
    int inc = cnt;
    #pragma unroll
    for (int off = 1; off < 64; off <<= 1) {
        int v = __shfl_up(inc, off);
        if (lane >= off) inc += v;
    }
    int deg = __shfl(inc, 63);
    int pos = inc - cnt;
    int idb = lane * 128;
    float ss0 = s_src[i], ss1 = s_src[N_NODES + i];
    float z0 = 0.f, z1 = 0.f;
    size_t rb = (size_t)i * CAPN;

    unsigned int w; int off;
    #pragma unroll
    for (int q = 0; q < 4; ++q) {
        w   = (q == 0) ? wq.x : (q == 1) ? wq.y : (q == 2) ? wq.z : wq.w;
        off = idb + q * 32;
        while (w) {
            int b = __ffs(w) - 1;
            w &= w - 1;
            if (pos < CAPN) {
                int j = off + b;
                float v0 = ss0 + s_dst[j];
                float v1 = ss1 + s_dst[N_NODES + j];
                float e0 = v0 > 0.f ? v0 : LRELU_A * v0;
                float e1 = v1 > 0.f ? v1 : LRELU_A * v1;
                float w0 = expf(e0) - 1.f;
                float w1 = expf(e1) - 1.f;
                nbrG[rb + pos] = (unsigned short)j;
                wG0[rb + pos]  = w0;
                wG1[rb + pos]  = w1;
                z0 += w0; z1 += w1;
            }
            ++pos;
        }
    }
    #pragma unroll
    for (int o = 32; o; o >>= 1) {
        z0 += __shfl_xor(z0, o);
        z1 += __shfl_xor(z1, o);
    }
    if (lane == 0) {
        degG[i] = deg < CAPN ? deg : CAPN;
        ZG0[i]  = (float)N_NODES + z0;
        ZG1[i]  = (float)N_NODES + z1;
    }
}

// =============================================================================
// K4: gather-only attention — block per row, thread t owns channel t.
// Stage CSR row to LDS (coalesced, 1 barrier), then ILP-16 gather chain.
// =============================================================================
__global__ __launch_bounds__(256) void k_gather(const unsigned short* __restrict__ nbrG,
                                                const float* __restrict__ wG0,
                                                const float* __restrict__ wG1,
                                                const int*   __restrict__ degG,
                                                const float* __restrict__ ZG0,
                                                const float* __restrict__ ZG1,
                                                const unsigned short* __restrict__ hb16,
                                                const float* __restrict__ S_all,
                                                float* __restrict__ out) {
    __shared__ unsigned short snb[CAPN];
    __shared__ float          sw0[CAPN];
    __shared__ float          sw1[CAPN];

    int i = blockIdx.x, t = threadIdx.x;
    size_t rb = (size_t)i * CAPN;
    int deg = degG[i];

    if (t < CAPN) {
        snb[t] = nbrG[rb + t];
        sw0[t] = wG0[rb + t];
        sw1[t] = wG1[rb + t];
    }
    float sa = S_all[t];
    float Zh = (t >= 128) ? ZG1[i] : ZG0[i];
    __syncthreads();

    const float* swh = (t >= 128) ? sw1 : sw0;
    float acc = 0.f;
    int k = 0;
    for (; k + 16 <= deg; k += 16) {
        float v[16];
        #pragma unroll
        for (int u = 0; u < 16; ++u)
            v[u] = bf(hb16[(int)snb[k + u] * CTOT + t]);
        #pragma unroll
        for (int u = 0; u < 16; ++u)
            acc = fmaf(swh[k + u], v[u], acc);
    }
    if (k + 8 <= deg) {
        float v[8];
        #pragma unroll
        for (int u = 0; u < 8; ++u)
            v[u] = bf(hb16[(int)snb[k + u] * CTOT + t]);
        #pragma unroll
        for (int u = 0; u < 8; ++u)
            acc = fmaf(swh[k + u], v[u], acc);
        k += 8;
    }
    if (k + 4 <= deg) {
        float v[4];
        #pragma unroll
        for (int u = 0; u < 4; ++u)
            v[u] = bf(hb16[(int)snb[k + u] * CTOT + t]);
        #pragma unroll
        for (int u = 0; u < 4; ++u)
            acc = fmaf(swh[k + u], v[u], acc);
        k += 4;
    }
    for (; k < deg; ++k)
        acc = fmaf(swh[k], bf(hb16[(int)snb[k] * CTOT + t]), acc);

    float o = (sa + acc) / Zh;
    o = o > 0.f ? o : expm1f(o);           // ELU (alpha=1)
    out[i * CTOT + t] = o;
}

// ---------------- launch ------------------------------------------------------
extern "C" void kernel_launch(void* const* d_in, const int* in_sizes, int n_in,
                              void* d_out, int out_size, void* d_ws, size_t ws_size,
                              hipStream_t stream) {
    const float* x  = (const float*)d_in[0];
    const float* W  = (const float*)d_in[1];
    const float* a  = (const float*)d_in[2];
    const int*   ei = (const int*)d_in[3];
    int E = in_sizes[3] / 2;
    float* out = (float*)d_out;

    char* ws = (char*)d_ws;
    size_t off = 0;
    auto alloc = [&](size_t bytes) { char* p = ws + off; off += (bytes + 255) & ~(size_t)255; return p; };
    unsigned int*   adjw  = (unsigned int*)  alloc((size_t)N_NODES * NWORDS * 4); // 8 MB
    float*          S_all = (float*)         alloc(CTOT * 4);
    float*          s_src = (float*)         alloc((size_t)NHEAD * N_NODES * 4);
    float*          s_dst = (float*)         alloc((size_t)NHEAD * N_NODES * 4);
    unsigned short* hb16  = (unsigned short*)alloc((size_t)N_NODES * CTOT * 2);  // 4 MB
    unsigned short* nbrG  = (unsigned short*)alloc((size_t)N_NODES * CAPN * 2);
    float*          wG0   = (float*)         alloc((size_t)N_NODES * CAPN * 4);
    float*          wG1   = (float*)         alloc((size_t)N_NODES * CAPN * 4);
    int*            degG  = (int*)           alloc((size_t)N_NODES * 4);
    float*          ZG0   = (float*)         alloc((size_t)N_NODES * 4);
    float*          ZG1   = (float*)         alloc((size_t)N_NODES * 4);

    int nbBuild = (E + 255) / 256;
    k_pre<<<2305, 256, 0, stream>>>(x, W, hb16, (float4*)adjw, (float4*)S_all);
    k_mid<<<nbBuild + 256, 256, 0, stream>>>(ei, E, nbBuild, adjw,
                                             (const uint2*)hb16, a, s_src, s_dst, S_all);
    k_cw<<<N_NODES / 4, 256, 0, stream>>>(adjw, s_src, s_dst, nbrG, wG0, wG1, degG, ZG0, ZG1);
    k_gather<<<N_NODES, 256, 0, stream>>>(nbrG, wG0, wG1, degG, ZG0, ZG1, hb16, S_all, out);
}

// Round 11
// 83.813 us; speedup vs baseline: 3.2277x; 1.0088x over previous
//
#include <hip/hip_runtime.h>
#include <hip/hip_bf16.h>

#define N_NODES 8192
#define DIN     256
#define DOUT    128
#define NHEAD   2
#define CTOT    256          // NHEAD*DOUT, flat channel dim
#define NWORDS  256          // N_NODES/32 bitmask words per row
#define LRELU_A 0.2f
#define CAP     512          // max supported degree (actual max ~66)
#define LDR     40           // LDS row stride (80B = 5x16B, ds_read_b128 conflict-free)

typedef __attribute__((ext_vector_type(8))) short bf16x8;
typedef __attribute__((ext_vector_type(4))) float f32x4;

__device__ __forceinline__ float bf(unsigned short u) {
    return __uint_as_float((unsigned)u << 16);
}
__device__ __forceinline__ unsigned short f2bf(float f) {
    unsigned u = __float_as_uint(f);
    u = (u + 0x7fffu + ((u >> 16) & 1u)) >> 16;
    return (unsigned short)u;
}
__device__ __forceinline__ unsigned pk(float a, float b) {
    return (unsigned)f2bf(a) | ((unsigned)f2bf(b) << 16);
}

// =============================================================================
// K1: b<512: MFMA GEMM 64x64 tile (2 blocks/CU) + per-tile score partials;
//     [512,2560): clear adj bitmask; [2560,2816): x column-sum partials.
// =============================================================================
__global__ __launch_bounds__(256) void k_pre(const float* __restrict__ x,
                                             const float* __restrict__ W,
                                             const float* __restrict__ a,
                                             unsigned short* __restrict__ hb16,
                                             float* __restrict__ sp_src,   // [4][8192]
                                             float* __restrict__ sp_dst,   // [4][8192]
                                             float* __restrict__ cxp,      // [256][256]
                                             float4* __restrict__ adjp) {
    __shared__ unsigned short As[64 * LDR];   // 5 KB
    __shared__ unsigned short Bs[64 * LDR];   // 5 KB
    int b = blockIdx.x, t = threadIdx.x;

    if (b >= 2560) {                      // x column-sum partials: 32 rows/block
        int p = b - 2560;
        float s = 0.f;
        int r0 = p * 32;
        #pragma unroll 8
        for (int r = r0; r < r0 + 32; ++r)
            s += x[r * DIN + t];
        cxp[p * 256 + t] = s;
        return;
    }
    if (b >= 512) {                       // clear 8 MB bitmask
        adjp[(b - 512) * 256 + t] = make_float4(0.f, 0.f, 0.f, 0.f);
        return;
    }

    // ---- GEMM tile 64x64 ----
    int bm = (b & 127) * 64;
    int bn = (b >> 7) * 64;
    int wv = t >> 6, lane = t & 63;
    int fr = lane & 15, ksl = lane >> 4;

    f32x4 acc[4] = {};
    for (int k0 = 0; k0 < DIN; k0 += 32) {
        {
            int row = t >> 2, slot = t & 3;
            const float4* srcA = reinterpret_cast<const float4*>(&x[(bm + row) * DIN + k0 + slot * 8]);
            float4 va0 = srcA[0], va1 = srcA[1];
            *reinterpret_cast<uint4*>(&As[row * LDR + slot * 8]) =
                make_uint4(pk(va0.x, va0.y), pk(va0.z, va0.w), pk(va1.x, va1.y), pk(va1.z, va1.w));
            const float4* srcB = reinterpret_cast<const float4*>(&W[(bn + row) * DIN + k0 + slot * 8]);
            float4 vb0 = srcB[0], vb1 = srcB[1];
            *reinterpret_cast<uint4*>(&Bs[row * LDR + slot * 8]) =
                make_uint4(pk(vb0.x, vb0.y), pk(vb0.z, vb0.w), pk(vb1.x, vb1.y), pk(vb1.z, vb1.w));
        }
        __syncthreads();
        bf16x8 af = *reinterpret_cast<const bf16x8*>(&As[(wv * 16 + fr) * LDR + ksl * 8]);
        #pragma unroll
        for (int fn = 0; fn < 4; ++fn) {
            bf16x8 bfr = *reinterpret_cast<const bf16x8*>(&Bs[(fn * 16 + fr) * LDR + ksl * 8]);
            acc[fn] = __builtin_amdgcn_mfma_f32_16x16x32_bf16(af, bfr, acc[fn], 0, 0, 0);
        }
        __syncthreads();
    }

    // ---- epilogue: hb16 write (C/D: col=fr, row=ksl*4+r) ----
    #pragma unroll
    for (int fn = 0; fn < 4; ++fn) {
        int c = bn + fn * 16 + fr;
        int r0 = bm + wv * 16 + ksl * 4;
        #pragma unroll
        for (int r = 0; r < 4; ++r)
            hb16[(size_t)(r0 + r) * CTOT + c] = f2bf(acc[fn][r]);
    }

    // ---- score partials: sp[q][row] = sum_{c in tile} h[row][c]*a_{src,dst}[c] ----
    int head = (bn >= 128);
    int q    = bn >> 6;
    float as[4], ad[4];
    #pragma unroll
    for (int fn = 0; fn < 4; ++fn) {
        int d = (bn & 127) + fn * 16 + fr;
        as[fn] = a[head * 256 + d];
        ad[fn] = a[head * 256 + 128 + d];
    }
    #pragma unroll
    for (int r = 0; r < 4; ++r) {
        float ps = acc[0][r] * as[0] + acc[1][r] * as[1] + acc[2][r] * as[2] + acc[3][r] * as[3];
        float pd = acc[0][r] * ad[0] + acc[1][r] * ad[1] + acc[2][r] * ad[2] + acc[3][r] * ad[3];
        #pragma unroll
        for (int off = 8; off; off >>= 1) {
            ps += __shfl_xor(ps, off);
            pd += __shfl_xor(pd, off);
        }
        if (fr == 0) {
            int row = bm + wv * 16 + ksl * 4 + r;
            sp_src[q * N_NODES + row] = ps;
            sp_dst[q * N_NODES + row] = pd;
        }
    }
}

// =============================================================================
// K2: b<1024: edge scatter (atomicOr dedup);
//     [1024,1056): score-partial reduce -> s_src, s_dst;
//     b==1056: S_all[c] = (sum_p cxp[p]) . W[c][:]  (single block).
// =============================================================================
__global__ __launch_bounds__(256) void k_mid(const int* __restrict__ ei, int E,
                                             unsigned int* __restrict__ adjw,
                                             const float* __restrict__ sp_src,
                                             const float* __restrict__ sp_dst,
                                             const float* __restrict__ cxp,
                                             const float* __restrict__ W,
                                             float* __restrict__ s_src,
                                             float* __restrict__ s_dst,
                                             float* __restrict__ S_all) {
    __shared__ float scx[256];
    int b = blockIdx.x, t = threadIdx.x;

    if (b < 1024) {                       // edge scatter
        int e = b * 256 + t;
        if (e < E) {
            int src = ei[e];
            int dst = ei[E + e];
            atomicOr(&adjw[(size_t)src * NWORDS + (dst >> 5)], 1u << (dst & 31));
        }
        return;
    }
    if (b < 1056) {                       // score reduce: n = (b-1024)*256 + t
        int n = (b - 1024) * 256 + t;
        s_src[n]           = sp_src[0 * N_NODES + n] + sp_src[1 * N_NODES + n];
        s_src[N_NODES + n] = sp_src[2 * N_NODES + n] + sp_src[3 * N_NODES + n];
        s_dst[n]           = sp_dst[0 * N_NODES + n] + sp_dst[1 * N_NODES + n];
        s_dst[N_NODES + n] = sp_dst[2 * N_NODES + n] + sp_dst[3 * N_NODES + n];
        return;
    }

    // ---- S_all: reduce cxp then matvec with W ----
    float s = 0.f;
    #pragma unroll 8
    for (int p = 0; p < 256; ++p)
        s += cxp[p * 256 + t];
    scx[t] = s;
    __syncthreads();

    int wv = t >> 6, lane = t & 63;
    float4 cx4 = *reinterpret_cast<const float4*>(&scx[lane * 4]);
    for (int cc = 0; cc < 64; ++cc) {
        int c = wv * 64 + cc;
        float4 w4 = *reinterpret_cast<const float4*>(&W[c * DIN + lane * 4]);
        float p = w4.x * cx4.x + w4.y * cx4.y + w4.z * cx4.z + w4.w * cx4.w;
        #pragma unroll
        for (int off = 32; off; off >>= 1)
            p += __shfl_xor(p, off);
        if (lane == 0) S_all[c] = p;
    }
}

// =============================================================================
// K3: attention row kernel (R8-proven): block per row, thread t owns channel t,
// in-LDS compaction + weights, ILP-8 bf16 gather.
// =============================================================================
__global__ __launch_bounds__(256) void k_attn(const unsigned int* __restrict__ adjw,
                                              const float* __restrict__ s_src,
                                              const float* __restrict__ s_dst,
                                              const unsigned short* __restrict__ hb16,
                                              const float* __restrict__ S_all,
                                              float* __restrict__ out) {
    __shared__ unsigned short nbr[CAP];
    __shared__ float          ew0[CAP];
    __shared__ float          ew1[CAP];
    __shared__ int            wtot[4];
    __shared__ float          zr0[4];
    __shared__ float          zr1[4];

    int i    = blockIdx.x;
    int t    = threadIdx.x;
    int lane = t & 63;
    int wv   = t >> 6;

    unsigned int w = adjw[(size_t)i * NWORDS + t];
    int cnt = __popc(w);
    int inc = cnt;
    #pragma unroll
    for (int off = 1; off < 64; off <<= 1) {
        int v = __shfl_up(inc, off);
        if (lane >= off) inc += v;
    }
    if (lane == 63) wtot[wv] = inc;
    __syncthreads();
    int base = 0;
    #pragma unroll
    for (int q = 0; q < 3; ++q) if (q < wv) base += wtot[q];
    int deg = wtot[0] + wtot[1] + wtot[2] + wtot[3];
    int pos = base + inc - cnt;
    unsigned int ww = w;
    while (ww) {
        int bb = __ffs(ww) - 1;
        ww &= ww - 1;
        if (pos < CAP) nbr[pos] = (unsigned short)(t * 32 + bb);
        ++pos;
    }
    if (deg > CAP) deg = CAP;
    __syncthreads();

    float ss0 = s_src[i], ss1 = s_src[N_NODES + i];
    float z0 = 0.f, z1 = 0.f;
    for (int k = t; k < deg; k += 256) {
        int j = nbr[k];
        float v0 = ss0 + s_dst[j];
        float v1 = ss1 + s_dst[N_NODES + j];
        float e0 = v0 > 0.f ? v0 : LRELU_A * v0;
        float e1 = v1 > 0.f ? v1 : LRELU_A * v1;
        float w0 = expf(e0) - 1.f;
        float w1 = expf(e1) - 1.f;
        ew0[k] = w0; ew1[k] = w1;
        z0 += w0; z1 += w1;
    }
    #pragma unroll
    for (int off = 32; off; off >>= 1) {
        z0 += __shfl_xor(z0, off);
        z1 += __shfl_xor(z1, off);
    }
    if (lane == 0) { zr0[wv] = z0; zr1[wv] = z1; }
    __syncthreads();
    float Z0 = (float)N_NODES + zr0[0] + zr0[1] + zr0[2] + zr0[3];
    float Z1 = (float)N_NODES + zr1[0] + zr1[1] + zr1[2] + zr1[3];

    int hh = t >> 7;
    const float* ewh = hh ? ew1 : ew0;
    float Zh = hh ? Z1 : Z0;
    float acc = 0.f;
    int k = 0;
    for (; k + 8 <= deg; k += 8) {
        int j0 = nbr[k+0], j1 = nbr[k+1], j2 = nbr[k+2], j3 = nbr[k+3];
        int j4 = nbr[k+4], j5 = nbr[k+5], j6 = nbr[k+6], j7 = nbr[k+7];
        float w0 = ewh[k+0], w1 = ewh[k+1], w2 = ewh[k+2], w3 = ewh[k+3];
        float w4 = ewh[k+4], w5 = ewh[k+5], w6 = ewh[k+6], w7 = ewh[k+7];
        float v0 = bf(hb16[j0 * CTOT + t]);
        float v1 = bf(hb16[j1 * CTOT + t]);
        float v2 = bf(hb16[j2 * CTOT + t]);
        float v3 = bf(hb16[j3 * CTOT + t]);
        float v4 = bf(hb16[j4 * CTOT + t]);
        float v5 = bf(hb16[j5 * CTOT + t]);
        float v6 = bf(hb16[j6 * CTOT + t]);
        float v7 = bf(hb16[j7 * CTOT + t]);
        acc = fmaf(w0, v0, acc); acc = fmaf(w1, v1, acc);
        acc = fmaf(w2, v2, acc); acc = fmaf(w3, v3, acc);
        acc = fmaf(w4, v4, acc); acc = fmaf(w5, v5, acc);
        acc = fmaf(w6, v6, acc); acc = fmaf(w7, v7, acc);
    }
    for (; k + 4 <= deg; k += 4) {
        int j0 = nbr[k], j1 = nbr[k+1], j2 = nbr[k+2], j3 = nbr[k+3];
        float w0 = ewh[k], w1 = ewh[k+1], w2 = ewh[k+2], w3 = ewh[k+3];
        float v0 = bf(hb16[j0 * CTOT + t]);
        float v1 = bf(hb16[j1 * CTOT + t]);
        float v2 = bf(hb16[j2 * CTOT + t]);
        float v3 = bf(hb16[j3 * CTOT + t]);
        acc = fmaf(w0, v0, acc); acc = fmaf(w1, v1, acc);
        acc = fmaf(w2, v2, acc); acc = fmaf(w3, v3, acc);
    }
    for (; k < deg; ++k)
        acc = fmaf(ewh[k], bf(hb16[nbr[k] * CTOT + t]), acc);

    float o = (S_all[t] + acc) / Zh;
    o = o > 0.f ? o : expm1f(o);           // ELU (alpha=1)
    out[i * CTOT + t] = o;
}

// ---------------- launch ------------------------------------------------------
extern "C" void kernel_launch(void* const* d_in, const int* in_sizes, int n_in,
                              void* d_out, int out_size, void* d_ws, size_t ws_size,
                              hipStream_t stream) {
    const float* x  = (const float*)d_in[0];
    const float* W  = (const float*)d_in[1];
    const float* a  = (const float*)d_in[2];
    const int*   ei = (const int*)d_in[3];
    int E = in_sizes[3] / 2;
    float* out = (float*)d_out;

    char* ws = (char*)d_ws;
    size_t off = 0;
    auto alloc = [&](size_t bytes) { char* p = ws + off; off += (bytes + 255) & ~(size_t)255; return p; };
    unsigned int*   adjw   = (unsigned int*)  alloc((size_t)N_NODES * NWORDS * 4); // 8 MB
    float*          S_all  = (float*)         alloc(CTOT * 4);
    float*          s_src  = (float*)         alloc((size_t)NHEAD * N_NODES * 4);
    float*          s_dst  = (float*)         alloc((size_t)NHEAD * N_NODES * 4);
    unsigned short* hb16   = (unsigned short*)alloc((size_t)N_NODES * CTOT * 2);  // 4 MB
    float*          sp_src = (float*)         alloc((size_t)4 * N_NODES * 4);     // 128 KB
    float*          sp_dst = (float*)         alloc((size_t)4 * N_NODES * 4);     // 128 KB
    float*          cxp    = (float*)         alloc((size_t)256 * 256 * 4);       // 256 KB

    k_pre<<<2816, 256, 0, stream>>>(x, W, a, hb16, sp_src, sp_dst, cxp, (float4*)adjw);
    k_mid<<<1057, 256, 0, stream>>>(ei, E, adjw, sp_src, sp_dst, cxp, W, s_src, s_dst, S_all);
    k_attn<<<N_NODES, 256, 0, stream>>>(adjw, s_src, s_dst, hb16, S_all, out);
}

// Round 12
// 66.318 us; speedup vs baseline: 4.0792x; 1.2638x over previous
//
#include <hip/hip_runtime.h>
#include <hip/hip_bf16.h>

#define N_NODES 8192
#define DIN     256
#define DOUT    128
#define NHEAD   2
#define CTOT    256          // NHEAD*DOUT, flat channel dim
#define NWORDS  256          // N_NODES/32 bitmask words per row
#define LRELU_A 0.2f
#define CAP     512          // max supported degree (actual max ~66)
#define LDR     40           // LDS row stride (80B = 5x16B, ds_read_b128 conflict-free)

typedef __attribute__((ext_vector_type(8))) short bf16x8;
typedef __attribute__((ext_vector_type(4))) float f32x4;

__device__ __forceinline__ float bf(unsigned short u) {
    return __uint_as_float((unsigned)u << 16);
}
__device__ __forceinline__ unsigned short f2bf(float f) {
    unsigned u = __float_as_uint(f);
    u = (u + 0x7fffu + ((u >> 16) & 1u)) >> 16;
    return (unsigned short)u;
}
__device__ __forceinline__ unsigned pk(float a, float b) {
    return (unsigned)f2bf(a) | ((unsigned)f2bf(b) << 16);
}

// =============================================================================
// K1: b<512: MFMA GEMM 64x64 tile (2 blocks/CU) + per-tile score partials;
//     [512,2560): clear adj bitmask; b==2560: clear S_all.
// =============================================================================
__global__ __launch_bounds__(256) void k_pre(const float* __restrict__ x,
                                             const float* __restrict__ W,
                                             const float* __restrict__ a,
                                             unsigned short* __restrict__ hb16,
                                             float* __restrict__ sp_src,   // [4][8192]
                                             float* __restrict__ sp_dst,   // [4][8192]
                                             float4* __restrict__ adjp,
                                             float4* __restrict__ sallp) {
    __shared__ unsigned short As[64 * LDR];   // 5 KB
    __shared__ unsigned short Bs[64 * LDR];   // 5 KB
    int b = blockIdx.x, t = threadIdx.x;

    if (b == 2560) {                      // clear S_all (256 floats)
        if (t < 64) sallp[t] = make_float4(0.f, 0.f, 0.f, 0.f);
        return;
    }
    if (b >= 512) {                       // clear 8 MB bitmask
        adjp[(b - 512) * 256 + t] = make_float4(0.f, 0.f, 0.f, 0.f);
        return;
    }

    // ---- GEMM tile 64x64 ----
    int bm = (b & 127) * 64;
    int bn = (b >> 7) * 64;
    int wv = t >> 6, lane = t & 63;
    int fr = lane & 15, ksl = lane >> 4;

    f32x4 acc[4] = {};
    for (int k0 = 0; k0 < DIN; k0 += 32) {
        {
            int row = t >> 2, slot = t & 3;
            const float4* srcA = reinterpret_cast<const float4*>(&x[(bm + row) * DIN + k0 + slot * 8]);
            float4 va0 = srcA[0], va1 = srcA[1];
            *reinterpret_cast<uint4*>(&As[row * LDR + slot * 8]) =
                make_uint4(pk(va0.x, va0.y), pk(va0.z, va0.w), pk(va1.x, va1.y), pk(va1.z, va1.w));
            const float4* srcB = reinterpret_cast<const float4*>(&W[(bn + row) * DIN + k0 + slot * 8]);
            float4 vb0 = srcB[0], vb1 = srcB[1];
            *reinterpret_cast<uint4*>(&Bs[row * LDR + slot * 8]) =
                make_uint4(pk(vb0.x, vb0.y), pk(vb0.z, vb0.w), pk(vb1.x, vb1.y), pk(vb1.z, vb1.w));
        }
        __syncthreads();
        bf16x8 af = *reinterpret_cast<const bf16x8*>(&As[(wv * 16 + fr) * LDR + ksl * 8]);
        #pragma unroll
        for (int fn = 0; fn < 4; ++fn) {
            bf16x8 bfr = *reinterpret_cast<const bf16x8*>(&Bs[(fn * 16 + fr) * LDR + ksl * 8]);
            acc[fn] = __builtin_amdgcn_mfma_f32_16x16x32_bf16(af, bfr, acc[fn], 0, 0, 0);
        }
        __syncthreads();
    }

    // ---- epilogue: hb16 write (C/D: col=fr, row=ksl*4+r) ----
    #pragma unroll
    for (int fn = 0; fn < 4; ++fn) {
        int c = bn + fn * 16 + fr;
        int r0 = bm + wv * 16 + ksl * 4;
        #pragma unroll
        for (int r = 0; r < 4; ++r)
            hb16[(size_t)(r0 + r) * CTOT + c] = f2bf(acc[fn][r]);
    }

    // ---- score partials: sp[q][row] = sum_{c in tile} h[row][c]*a_{src,dst}[c] ----
    int head = (bn >= 128);
    int q    = bn >> 6;
    float as[4], ad[4];
    #pragma unroll
    for (int fn = 0; fn < 4; ++fn) {
        int d = (bn & 127) + fn * 16 + fr;
        as[fn] = a[head * 256 + d];
        ad[fn] = a[head * 256 + 128 + d];
    }
    #pragma unroll
    for (int r = 0; r < 4; ++r) {
        float ps = acc[0][r] * as[0] + acc[1][r] * as[1] + acc[2][r] * as[2] + acc[3][r] * as[3];
        float pd = acc[0][r] * ad[0] + acc[1][r] * ad[1] + acc[2][r] * ad[2] + acc[3][r] * ad[3];
        #pragma unroll
        for (int off = 8; off; off >>= 1) {
            ps += __shfl_xor(ps, off);
            pd += __shfl_xor(pd, off);
        }
        if (fr == 0) {
            int row = bm + wv * 16 + ksl * 4 + r;
            sp_src[q * N_NODES + row] = ps;
            sp_dst[q * N_NODES + row] = pd;
        }
    }
}

// =============================================================================
// K2: b<1024: edge scatter (atomicOr dedup);
//     [1024,1056): score-partial reduce -> s_src, s_dst;
//     [1056,1568): colsum over hb16 -> atomicAdd S_all (16 rows/block).
// =============================================================================
__global__ __launch_bounds__(256) void k_mid(const int* __restrict__ ei, int E,
                                             unsigned int* __restrict__ adjw,
                                             const float* __restrict__ sp_src,
                                             const float* __restrict__ sp_dst,
                                             const unsigned short* __restrict__ hb16,
                                             float* __restrict__ s_src,
                                             float* __restrict__ s_dst,
                                             float* __restrict__ S_all) {
    int b = blockIdx.x, t = threadIdx.x;

    if (b < 1024) {                       // edge scatter
        int e = b * 256 + t;
        if (e < E) {
            int src = ei[e];
            int dst = ei[E + e];
            atomicOr(&adjw[(size_t)src * NWORDS + (dst >> 5)], 1u << (dst & 31));
        }
        return;
    }
    if (b < 1056) {                       // score reduce: n = (b-1024)*256 + t
        int n = (b - 1024) * 256 + t;
        s_src[n]           = sp_src[0 * N_NODES + n] + sp_src[1 * N_NODES + n];
        s_src[N_NODES + n] = sp_src[2 * N_NODES + n] + sp_src[3 * N_NODES + n];
        s_dst[n]           = sp_dst[0 * N_NODES + n] + sp_dst[1 * N_NODES + n];
        s_dst[N_NODES + n] = sp_dst[2 * N_NODES + n] + sp_dst[3 * N_NODES + n];
        return;
    }

    // ---- colsum: 512 blocks x 16 rows, one atomic per thread ----
    int r0 = (b - 1056) * 16;
    float s = 0.f;
    #pragma unroll
    for (int r = r0; r < r0 + 16; ++r)
        s += bf(hb16[r * CTOT + t]);
    atomicAdd(&S_all[t], s);
}

// =============================================================================
// K3: attention row kernel (R8-proven): block per row, thread t owns channel t,
// in-LDS compaction + weights, ILP-8 bf16 gather.
// =============================================================================
__global__ __launch_bounds__(256) void k_attn(const unsigned int* __restrict__ adjw,
                                              const float* __restrict__ s_src,
                                              const float* __restrict__ s_dst,
                                              const unsigned short* __restrict__ hb16,
                                              const float* __restrict__ S_all,
                                              float* __restrict__ out) {
    __shared__ unsigned short nbr[CAP];
    __shared__ float          ew0[CAP];
    __shared__ float          ew1[CAP];
    __shared__ int            wtot[4];
    __shared__ float          zr0[4];
    __shared__ float          zr1[4];

    int i    = blockIdx.x;
    int t    = threadIdx.x;
    int lane = t & 63;
    int wv   = t >> 6;

    unsigned int w = adjw[(size_t)i * NWORDS + t];
    int cnt = __popc(w);
    int inc = cnt;
    #pragma unroll
    for (int off = 1; off < 64; off <<= 1) {
        int v = __shfl_up(inc, off);
        if (lane >= off) inc += v;
    }
    if (lane == 63) wtot[wv] = inc;
    __syncthreads();
    int base = 0;
    #pragma unroll
    for (int q = 0; q < 3; ++q) if (q < wv) base += wtot[q];
    int deg = wtot[0] + wtot[1] + wtot[2] + wtot[3];
    int pos = base + inc - cnt;
    unsigned int ww = w;
    while (ww) {
        int bb = __ffs(ww) - 1;
        ww &= ww - 1;
        if (pos < CAP) nbr[pos] = (unsigned short)(t * 32 + bb);
        ++pos;
    }
    if (deg > CAP) deg = CAP;
    __syncthreads();

    float ss0 = s_src[i], ss1 = s_src[N_NODES + i];
    float z0 = 0.f, z1 = 0.f;
    for (int k = t; k < deg; k += 256) {
        int j = nbr[k];
        float v0 = ss0 + s_dst[j];
        float v1 = ss1 + s_dst[N_NODES + j];
        float e0 = v0 > 0.f ? v0 : LRELU_A * v0;
        float e1 = v1 > 0.f ? v1 : LRELU_A * v1;
        float w0 = expf(e0) - 1.f;
        float w1 = expf(e1) - 1.f;
        ew0[k] = w0; ew1[k] = w1;
        z0 += w0; z1 += w1;
    }
    #pragma unroll
    for (int off = 32; off; off >>= 1) {
        z0 += __shfl_xor(z0, off);
        z1 += __shfl_xor(z1, off);
    }
    if (lane == 0) { zr0[wv] = z0; zr1[wv] = z1; }
    __syncthreads();
    float Z0 = (float)N_NODES + zr0[0] + zr0[1] + zr0[2] + zr0[3];
    float Z1 = (float)N_NODES + zr1[0] + zr1[1] + zr1[2] + zr1[3];

    int hh = t >> 7;
    const float* ewh = hh ? ew1 : ew0;
    float Zh = hh ? Z1 : Z0;
    float acc = 0.f;
    int k = 0;
    for (; k + 8 <= deg; k += 8) {
        int j0 = nbr[k+0], j1 = nbr[k+1], j2 = nbr[k+2], j3 = nbr[k+3];
        int j4 = nbr[k+4], j5 = nbr[k+5], j6 = nbr[k+6], j7 = nbr[k+7];
        float w0 = ewh[k+0], w1 = ewh[k+1], w2 = ewh[k+2], w3 = ewh[k+3];
        float w4 = ewh[k+4], w5 = ewh[k+5], w6 = ewh[k+6], w7 = ewh[k+7];
        float v0 = bf(hb16[j0 * CTOT + t]);
        float v1 = bf(hb16[j1 * CTOT + t]);
        float v2 = bf(hb16[j2 * CTOT + t]);
        float v3 = bf(hb16[j3 * CTOT + t]);
        float v4 = bf(hb16[j4 * CTOT + t]);
        float v5 = bf(hb16[j5 * CTOT + t]);
        float v6 = bf(hb16[j6 * CTOT + t]);
        float v7 = bf(hb16[j7 * CTOT + t]);
        acc = fmaf(w0, v0, acc); acc = fmaf(w1, v1, acc);
        acc = fmaf(w2, v2, acc); acc = fmaf(w3, v3, acc);
        acc = fmaf(w4, v4, acc); acc = fmaf(w5, v5, acc);
        acc = fmaf(w6, v6, acc); acc = fmaf(w7, v7, acc);
    }
    for (; k + 4 <= deg; k += 4) {
        int j0 = nbr[k], j1 = nbr[k+1], j2 = nbr[k+2], j3 = nbr[k+3];
        float w0 = ewh[k], w1 = ewh[k+1], w2 = ewh[k+2], w3 = ewh[k+3];
        float v0 = bf(hb16[j0 * CTOT + t]);
        float v1 = bf(hb16[j1 * CTOT + t]);
        float v2 = bf(hb16[j2 * CTOT + t]);
        float v3 = bf(hb16[j3 * CTOT + t]);
        acc = fmaf(w0, v0, acc); acc = fmaf(w1, v1, acc);
        acc = fmaf(w2, v2, acc); acc = fmaf(w3, v3, acc);
    }
    for (; k < deg; ++k)
        acc = fmaf(ewh[k], bf(hb16[nbr[k] * CTOT + t]), acc);

    float o = (S_all[t] + acc) / Zh;
    o = o > 0.f ? o : expm1f(o);           // ELU (alpha=1)
    out[i * CTOT + t] = o;
}

// ---------------- launch ------------------------------------------------------
extern "C" void kernel_launch(void* const* d_in, const int* in_sizes, int n_in,
                              void* d_out, int out_size, void* d_ws, size_t ws_size,
                              hipStream_t stream) {
    const float* x  = (const float*)d_in[0];
    const float* W  = (const float*)d_in[1];
    const float* a  = (const float*)d_in[2];
    const int*   ei = (const int*)d_in[3];
    int E = in_sizes[3] / 2;
    float* out = (float*)d_out;

    char* ws = (char*)d_ws;
    size_t off = 0;
    auto alloc = [&](size_t bytes) { char* p = ws + off; off += (bytes + 255) & ~(size_t)255; return p; };
    unsigned int*   adjw   = (unsigned int*)  alloc((size_t)N_NODES * NWORDS * 4); // 8 MB
    float*          S_all  = (float*)         alloc(CTOT * 4);
    float*          s_src  = (float*)         alloc((size_t)NHEAD * N_NODES * 4);
    float*          s_dst  = (float*)         alloc((size_t)NHEAD * N_NODES * 4);
    unsigned short* hb16   = (unsigned short*)alloc((size_t)N_NODES * CTOT * 2);  // 4 MB
    float*          sp_src = (float*)         alloc((size_t)4 * N_NODES * 4);     // 128 KB
    float*          sp_dst = (float*)         alloc((size_t)4 * N_NODES * 4);     // 128 KB

    k_pre<<<2561, 256, 0, stream>>>(x, W, a, hb16, sp_src, sp_dst, (float4*)adjw, (float4*)S_all);
    k_mid<<<1568, 256, 0, stream>>>(ei, E, adjw, sp_src, sp_dst, hb16, s_src, s_dst, S_all);
    k_attn<<<N_NODES, 256, 0, stream>>>(adjw, s_src, s_dst, hb16, S_all, out);
}